// Round 5
// baseline (183.845 us; speedup 1.0000x reference)
//
#include <hip/hip_runtime.h>
#include <stdint.h>

#define T_SEQ 4096
#define NB 2
#define D_MODEL 2048
#define HD 128

typedef __attribute__((ext_vector_type(4)))  float f32x4;
typedef __attribute__((ext_vector_type(16))) float f32x16;
typedef __attribute__((ext_vector_type(8)))  short bf16x8;
typedef __attribute__((ext_vector_type(4)))  unsigned u32x4;

#define LAMBDA_INIT 0.7836057665316244f
#define OUT_SCALE   0.21639423346837556f

__device__ __forceinline__ unsigned short f2bf(float f) {
  unsigned int u = __float_as_uint(f);
  u += 0x7FFFu + ((u >> 16) & 1u);
  return (unsigned short)(u >> 16);
}
__device__ __forceinline__ float bf2f(unsigned short h) {
  return __uint_as_float(((unsigned int)h) << 16);
}
__device__ __forceinline__ unsigned cvt_pk_bf16(float a, float b) {
  unsigned r;
  asm("v_cvt_pk_bf16_f32 %0, %1, %2" : "=v"(r) : "v"(a), "v"(b));
  return r;
}

// ---------------- Kernel 0: transpose+cast W -> wT[which][n][k] bf16 -------
// q weight gets SCALE=0.125 folded (exact power of 2).
__global__ __launch_bounds__(128) void wtrans(
    const float* __restrict__ wq, const float* __restrict__ wk,
    const float* __restrict__ wv, unsigned short* __restrict__ wT)
{
  const int which = blockIdx.y;
  const float* w = (which == 0) ? wq : ((which == 1) ? wk : wv);
  const int kc = blockIdx.x * 16;
  const int n  = threadIdx.x;
  float v[16];
  #pragma unroll
  for (int j = 0; j < 16; ++j) v[j] = w[(size_t)(kc + j) * HD + n];
  if (which == 0) {
    #pragma unroll
    for (int j = 0; j < 16; ++j) v[j] *= 0.125f;
  }
  u32x4 u0, u1;
  #pragma unroll
  for (int j = 0; j < 4; ++j) u0[j] = cvt_pk_bf16(v[2 * j], v[2 * j + 1]);
  #pragma unroll
  for (int j = 0; j < 4; ++j) u1[j] = cvt_pk_bf16(v[8 + 2 * j], v[9 + 2 * j]);
  unsigned short* o = wT + ((size_t)which * HD + n) * D_MODEL + kc;
  *reinterpret_cast<u32x4*>(o)     = u0;
  *reinterpret_cast<u32x4*>(o + 8) = u1;
}

// ---------------- Kernel 1: fused QKV projection --------------------------
// grid 256 (M-tile 32). x staged once in LDS; B-fragments read directly
// from L2-resident wT. 4 waves = 2(m) x 2(n).
#define K1_LDP 40

__global__ __launch_bounds__(256) void qkv_proj(
    const float* __restrict__ x, const unsigned short* __restrict__ wT,
    unsigned short* __restrict__ qb, unsigned short* __restrict__ kb,
    unsigned short* __restrict__ vt)
{
  __shared__ __align__(16) unsigned short Ah[32 * K1_LDP];
  const int m0 = blockIdx.x * 32;
  const int tid = threadIdx.x;
  const int lane = tid & 63, wid = tid >> 6;
  const int wm = wid >> 1, wn = wid & 1;        // wave tile 16(m) x 64(n)
  const int fr = lane & 15, fq = lane >> 4;
  const int fk = fq << 3;
  const int ar = tid >> 3, ac = (tid & 7) << 2; // A staging coords

  const unsigned short* wtq = wT;
  const unsigned short* wtk = wT + (size_t)HD * D_MODEL;
  const unsigned short* wtv = wT + (size_t)2 * HD * D_MODEL;

  f32x4 accq[4], acck[4], accv[4];
  #pragma unroll
  for (int j = 0; j < 4; ++j) {
    accq[j] = (f32x4){0.f, 0.f, 0.f, 0.f};
    acck[j] = (f32x4){0.f, 0.f, 0.f, 0.f};
    accv[j] = (f32x4){0.f, 0.f, 0.f, 0.f};
  }

  f32x4 arg = *reinterpret_cast<const f32x4*>(&x[(size_t)(m0 + ar) * D_MODEL + ac]);

  for (int it = 0; it < 64; ++it) {
    const int k0 = it * 32;
    uint2 ph;
    ph.x = cvt_pk_bf16(arg[0], arg[1]);
    ph.y = cvt_pk_bf16(arg[2], arg[3]);
    *reinterpret_cast<uint2*>(&Ah[ar * K1_LDP + ac]) = ph;
    __syncthreads();
    if (it < 63)
      arg = *reinterpret_cast<const f32x4*>(&x[(size_t)(m0 + ar) * D_MODEL + k0 + 32 + ac]);
    // B fragments direct from wT (row n, k = k0 + fq*8)
    bf16x8 bq[4], bk[4], bv[4];
    #pragma unroll
    for (int ni = 0; ni < 4; ++ni) {
      size_t roff = (size_t)(wn * 64 + ni * 16 + fr) * D_MODEL + k0 + fk;
      bq[ni] = *reinterpret_cast<const bf16x8*>(wtq + roff);
      bk[ni] = *reinterpret_cast<const bf16x8*>(wtk + roff);
      bv[ni] = *reinterpret_cast<const bf16x8*>(wtv + roff);
    }
    bf16x8 ah = *reinterpret_cast<bf16x8*>(&Ah[(wm * 16 + fr) * K1_LDP + fk]);
    #pragma unroll
    for (int ni = 0; ni < 4; ++ni) {
      accq[ni] = __builtin_amdgcn_mfma_f32_16x16x32_bf16(ah, bq[ni], accq[ni], 0, 0, 0);
      acck[ni] = __builtin_amdgcn_mfma_f32_16x16x32_bf16(ah, bk[ni], acck[ni], 0, 0, 0);
      accv[ni] = __builtin_amdgcn_mfma_f32_16x16x32_bf16(ah, bv[ni], accv[ni], 0, 0, 0);
    }
    __syncthreads();
  }
  #pragma unroll
  for (int ni = 0; ni < 4; ++ni) {
    int nn = wn * 64 + ni * 16 + fr;
    #pragma unroll
    for (int r = 0; r < 4; ++r) {
      int m = m0 + wm * 16 + fq * 4 + r;
      size_t idx = (size_t)m * HD + nn;
      qb[idx] = f2bf(accq[ni][r]);
      kb[idx] = f2bf(acck[ni][r]);
      int bb = m >> 12, t = m & 4095;
      vt[((size_t)bb * HD + nn) * T_SEQ + t] = f2bf(accv[ni][r]);
    }
  }
}

// ---------------- Kernel 2: per-wave flash partials -----------------------
// wave decodes (b, qt_raw, g, sp); qt = 127 - qt_raw so heavy tiles launch
// first. Partial slot re-encoded from reversed qt (bijective). K prefetch
// one tile ahead; V loaded early; no LDS, no syncthreads.
template<int LOG2S>
__global__ __launch_bounds__(256, 2) void diff_attn_part(
    const unsigned short* __restrict__ qb, const unsigned short* __restrict__ kb,
    const unsigned short* __restrict__ vt,
    unsigned short* __restrict__ po, float* __restrict__ pm, float* __restrict__ pl)
{
  constexpr int S = 1 << LOG2S;
  const int tid = threadIdx.x, lane = tid & 63, wid = tid >> 6;
  const int wave_id = blockIdx.x * 4 + wid;
  const int sp = wave_id & (S - 1);
  const int g  = (wave_id >> LOG2S) & 1;
  const int qt_raw = (wave_id >> (LOG2S + 1)) & 127;
  const int b  = wave_id >> (LOG2S + 8);
  const int qt = 127 - qt_raw;                  // heavy-first scheduling
  const int slot = (((b * 128 + qt) * 2 + g) << LOG2S) + sp;
  const int lq = lane & 31, lh = lane >> 5;
  const int q0 = qt * 32;
  const int n  = qt + 1;
  const int kt0 = (n * sp) >> LOG2S;
  const int kt1 = (n * (sp + 1)) >> LOG2S;

  // Q as B-operand: col=q=lq, k = ks*16 + lh*8 + e
  bf16x8 qf[4];
  const unsigned short* qp = qb + ((size_t)b * T_SEQ + q0 + lq) * HD + g * 64 + lh * 8;
  #pragma unroll
  for (int ks = 0; ks < 4; ++ks) qf[ks] = *reinterpret_cast<const bf16x8*>(qp + ks * 16);

  f32x16 acc[4];
  #pragma unroll
  for (int v = 0; v < 4; ++v)
    #pragma unroll
    for (int r = 0; r < 16; ++r) acc[v][r] = 0.f;
  float mrun = -1e30f, lrun = 0.f;

  const unsigned short* kp = kb + ((size_t)b * T_SEQ + lq) * HD + g * 64 + lh * 8;
  const unsigned short* vp = vt + ((size_t)b * HD + lq) * T_SEQ + lh * 8;

  bf16x8 kf[4];
  if (kt0 < kt1) {
    #pragma unroll
    for (int ks = 0; ks < 4; ++ks)
      kf[ks] = *reinterpret_cast<const bf16x8*>(kp + (size_t)kt0 * 32 * HD + ks * 16);
  }

  for (int kt = kt0; kt < kt1; ++kt) {
    const int kv0 = kt * 32;
    // V loads for this tile + K loads for next tile: issued before the
    // compute so their L2 latency hides under softmax VALU.
    bf16x8 vfa[4], vfb[4];
    #pragma unroll
    for (int vcb = 0; vcb < 4; ++vcb) {
      vfa[vcb] = *reinterpret_cast<const bf16x8*>(vp + (size_t)vcb * 32 * T_SEQ + kv0);
      vfb[vcb] = *reinterpret_cast<const bf16x8*>(vp + (size_t)vcb * 32 * T_SEQ + kv0 + 16);
    }
    bf16x8 kfn[4];
    const bool more = (kt + 1 < kt1);
    if (more) {
      #pragma unroll
      for (int ks = 0; ks < 4; ++ks)
        kfn[ks] = *reinterpret_cast<const bf16x8*>(kp + (size_t)(kv0 + 32) * HD + ks * 16);
    }
    // QK^T (kf arrived: loaded one iteration ago)
    f32x16 sc;
    #pragma unroll
    for (int r = 0; r < 16; ++r) sc[r] = 0.f;
    #pragma unroll
    for (int ks = 0; ks < 4; ++ks)
      sc = __builtin_amdgcn_mfma_f32_32x32x16_bf16(kf[ks], qf[ks], sc, 0, 0, 0);

    float p[16];
    if (kt == n - 1) {      // diagonal tile: mask kv_local > q_local
      #pragma unroll
      for (int r = 0; r < 16; ++r) {
        int rloc = (r & 3) + 8 * (r >> 2) + 4 * lh;
        p[r] = (rloc > lq) ? -1e30f : sc[r];
      }
    } else {
      #pragma unroll
      for (int r = 0; r < 16; ++r) p[r] = sc[r];
    }
    // column max over 32 rows (16 local + partner half)
    float t16[16];
    #pragma unroll
    for (int r = 0; r < 16; ++r) t16[r] = p[r];
    #pragma unroll
    for (int st = 8; st >= 1; st >>= 1)
      #pragma unroll
      for (int r = 0; r < 8; ++r)
        if (r < st) t16[r] = fmaxf(t16[r], t16[r + st]);
    float pmax = fmaxf(t16[0], __shfl_xor(t16[0], 32));
    if (__any(pmax > mrun + 8.f)) {          // T13 defer-max
      float mn = fmaxf(mrun, pmax);
      float al = __expf(mrun - mn);
      lrun *= al;
      #pragma unroll
      for (int v = 0; v < 4; ++v)
        #pragma unroll
        for (int r = 0; r < 16; ++r) acc[v][r] *= al;
      mrun = mn;
    }
    float psum;
    {
      float s16[16];
      #pragma unroll
      for (int r = 0; r < 16; ++r) { p[r] = __expf(p[r] - mrun); s16[r] = p[r]; }
      #pragma unroll
      for (int st = 8; st >= 1; st >>= 1)
        #pragma unroll
        for (int r = 0; r < 8; ++r)
          if (r < st) s16[r] += s16[r + st];
      psum = s16[0];
    }
    lrun += psum + __shfl_xor(psum, 32);     // full column sum

    // pack P -> B-frags via partner exchange (shfl_xor 32)
    unsigned A0 = cvt_pk_bf16(p[0],  p[1]),  A1 = cvt_pk_bf16(p[2],  p[3]);
    unsigned A2 = cvt_pk_bf16(p[4],  p[5]),  A3 = cvt_pk_bf16(p[6],  p[7]);
    unsigned A4 = cvt_pk_bf16(p[8],  p[9]),  A5 = cvt_pk_bf16(p[10], p[11]);
    unsigned A6 = cvt_pk_bf16(p[12], p[13]), A7 = cvt_pk_bf16(p[14], p[15]);
    unsigned pA0 = (unsigned)__shfl_xor((int)A0, 32);
    unsigned pA1 = (unsigned)__shfl_xor((int)A1, 32);
    unsigned pA2 = (unsigned)__shfl_xor((int)A2, 32);
    unsigned pA3 = (unsigned)__shfl_xor((int)A3, 32);
    unsigned pA4 = (unsigned)__shfl_xor((int)A4, 32);
    unsigned pA5 = (unsigned)__shfl_xor((int)A5, 32);
    unsigned pA6 = (unsigned)__shfl_xor((int)A6, 32);
    unsigned pA7 = (unsigned)__shfl_xor((int)A7, 32);
    u32x4 w0, w1;
    w0[0] = lh ? pA2 : A0;  w0[1] = lh ? pA3 : A1;
    w0[2] = lh ? A2  : pA0; w0[3] = lh ? A3  : pA1;
    w1[0] = lh ? pA6 : A4;  w1[1] = lh ? pA7 : A5;
    w1[2] = lh ? A6  : pA4; w1[3] = lh ? A7  : pA5;
    bf16x8 pb0 = *reinterpret_cast<bf16x8*>(&w0);
    bf16x8 pb1 = *reinterpret_cast<bf16x8*>(&w1);
    // PV (O^T = V^T * P), V already in regs
    #pragma unroll
    for (int vcb = 0; vcb < 4; ++vcb) {
      acc[vcb] = __builtin_amdgcn_mfma_f32_32x32x16_bf16(vfa[vcb], pb0, acc[vcb], 0, 0, 0);
      acc[vcb] = __builtin_amdgcn_mfma_f32_32x32x16_bf16(vfb[vcb], pb1, acc[vcb], 0, 0, 0);
    }
    if (more) {
      #pragma unroll
      for (int ks = 0; ks < 4; ++ks) kf[ks] = kfn[ks];
    }
  }
  // write partial: o^T[vc][q] bf16 + stats
  const size_t pbase = (size_t)slot * (HD * 32);
  #pragma unroll
  for (int vcb = 0; vcb < 4; ++vcb)
    #pragma unroll
    for (int r = 0; r < 16; ++r) {
      int vc = vcb * 32 + (r & 3) + 8 * (r >> 2) + 4 * lh;
      po[pbase + (size_t)vc * 32 + lq] = f2bf(acc[vcb][r]);
    }
  if (lane < 32) {
    pm[slot * 32 + lq] = mrun;
    pl[slot * 32 + lq] = lrun;
  }
}

// ---------------- Kernel 3: merge partials + diff + RMS + store -----------
template<int LOG2S>
__global__ __launch_bounds__(256) void diff_merge(
    const unsigned short* __restrict__ po, const float* __restrict__ pm,
    const float* __restrict__ pl,
    const float* __restrict__ lq1, const float* __restrict__ lq2,
    const float* __restrict__ lk1, const float* __restrict__ lk2,
    const float* __restrict__ lnw, float* __restrict__ out)
{
  constexpr int S = 1 << LOG2S;
  __shared__ float red[4][32];
  const int tid = threadIdx.x, lane = tid & 63, wid = tid >> 6;
  const int q = tid & 31, vg = tid >> 5;       // vc = vg*16 + i
  const int bq = blockIdx.x;                    // b*128 + qt
  const int b = bq >> 7, qt = bq & 127;

  float la = lq1[lane] * lk1[lane];
  float lb = lq2[lane] * lk2[lane];
  #pragma unroll
  for (int off = 32; off >= 1; off >>= 1) {
    la += __shfl_xor(la, off);
    lb += __shfl_xor(lb, off);
  }
  const float lam = __expf(la) - __expf(lb) + LAMBDA_INIT;

  const int p1 = (bq * 2 + 0) * S;
  const int p2 = (bq * 2 + 1) * S;
  float w1[S], w2[S];
  {
    float ms[S];
    #pragma unroll
    for (int s = 0; s < S; ++s) ms[s] = pm[(p1 + s) * 32 + q];
    float M = ms[0];
    #pragma unroll
    for (int s = 1; s < S; ++s) M = fmaxf(M, ms[s]);
    float L = 0.f;
    #pragma unroll
    for (int s = 0; s < S; ++s) { w1[s] = __expf(ms[s] - M); L += w1[s] * pl[(p1 + s) * 32 + q]; }
    float inv = 1.f / L;
    #pragma unroll
    for (int s = 0; s < S; ++s) w1[s] *= inv;
  }
  {
    float ms[S];
    #pragma unroll
    for (int s = 0; s < S; ++s) ms[s] = pm[(p2 + s) * 32 + q];
    float M = ms[0];
    #pragma unroll
    for (int s = 1; s < S; ++s) M = fmaxf(M, ms[s]);
    float L = 0.f;
    #pragma unroll
    for (int s = 0; s < S; ++s) { w2[s] = __expf(ms[s] - M); L += w2[s] * pl[(p2 + s) * 32 + q]; }
    float inv = lam / L;
    #pragma unroll
    for (int s = 0; s < S; ++s) w2[s] *= inv;
  }
  float d[16], ss = 0.f;
  #pragma unroll
  for (int i = 0; i < 16; ++i) {
    int vc = vg * 16 + i;
    float a1 = 0.f, a2 = 0.f;
    #pragma unroll
    for (int s = 0; s < S; ++s) {
      a1 += w1[s] * bf2f(po[(size_t)(p1 + s) * (HD * 32) + (size_t)vc * 32 + q]);
      a2 += w2[s] * bf2f(po[(size_t)(p2 + s) * (HD * 32) + (size_t)vc * 32 + q]);
    }
    d[i] = a1 - a2;
    ss += d[i] * d[i];
  }
  ss += __shfl_xor(ss, 32);
  if (lane < 32) red[wid][q] = ss;
  __syncthreads();
  float tot = red[0][q] + red[1][q] + red[2][q] + red[3][q];
  float rinv = 1.f / sqrtf(tot * (1.0f / HD) + 1e-5f);
  float* op = out + ((size_t)b * T_SEQ + qt * 32 + q) * HD + vg * 16;
  #pragma unroll
  for (int i = 0; i < 16; ++i) op[i] = OUT_SCALE * d[i] * rinv * lnw[vg * 16 + i];
}

extern "C" void kernel_launch(void* const* d_in, const int* in_sizes, int n_in,
                              void* d_out, int out_size, void* d_ws, size_t ws_size,
                              hipStream_t stream) {
  const float* x   = (const float*)d_in[0];
  const float* wq  = (const float*)d_in[1];
  const float* wk  = (const float*)d_in[2];
  const float* wv  = (const float*)d_in[3];
  const float* lq1 = (const float*)d_in[4];
  const float* lq2 = (const float*)d_in[5];
  const float* lk1 = (const float*)d_in[6];
  const float* lk2 = (const float*)d_in[7];
  const float* lnw = (const float*)d_in[8];
  float* out = (float*)d_out;

  const size_t N = (size_t)NB * T_SEQ * HD;     // 1,048,576
  const size_t WTN = (size_t)3 * HD * D_MODEL;  // 786,432
  int log2S = 3;
  for (; log2S > 0; --log2S) {
    size_t parts = ((size_t)NB * 128 * 2) << log2S;
    size_t need = 3 * N * 2 + WTN * 2 + parts * (HD * 32) * 2 + parts * 32 * 8;
    if (need <= ws_size) break;
  }
  const size_t parts = ((size_t)NB * 128 * 2) << log2S;

  unsigned short* qb = (unsigned short*)d_ws;
  unsigned short* kb = qb + N;
  unsigned short* vt = kb + N;
  unsigned short* wT = vt + N;
  unsigned short* po = wT + WTN;
  float* pm = (float*)(po + parts * (HD * 32));
  float* pl = pm + parts * 32;

  wtrans<<<dim3(128, 3), 128, 0, stream>>>(wq, wk, wv, wT);
  qkv_proj<<<dim3(256), 256, 0, stream>>>(x, wT, qb, kb, vt);
  const int ablocks = (int)(parts / 4);
  switch (log2S) {
    case 3:
      diff_attn_part<3><<<dim3(ablocks), 256, 0, stream>>>(qb, kb, vt, po, pm, pl);
      diff_merge<3><<<dim3(NB * 128), 256, 0, stream>>>(po, pm, pl, lq1, lq2, lk1, lk2, lnw, out);
      break;
    case 2:
      diff_attn_part<2><<<dim3(ablocks), 256, 0, stream>>>(qb, kb, vt, po, pm, pl);
      diff_merge<2><<<dim3(NB * 128), 256, 0, stream>>>(po, pm, pl, lq1, lq2, lk1, lk2, lnw, out);
      break;
    case 1:
      diff_attn_part<1><<<dim3(ablocks), 256, 0, stream>>>(qb, kb, vt, po, pm, pl);
      diff_merge<1><<<dim3(NB * 128), 256, 0, stream>>>(po, pm, pl, lq1, lq2, lk1, lk2, lnw, out);
      break;
    default:
      diff_attn_part<0><<<dim3(ablocks), 256, 0, stream>>>(qb, kb, vt, po, pm, pl);
      diff_merge<0><<<dim3(NB * 128), 256, 0, stream>>>(po, pm, pl, lq1, lq2, lk1, lk2, lnw, out);
      break;
  }
}

// Round 6
// 122.146 us; speedup vs baseline: 1.5051x; 1.5051x over previous
//
#include <hip/hip_runtime.h>
#include <stdint.h>

#define T_SEQ 4096
#define NB 2
#define D_MODEL 2048
#define HD 128

typedef __attribute__((ext_vector_type(4)))  float f32x4;
typedef __attribute__((ext_vector_type(16))) float f32x16;
typedef __attribute__((ext_vector_type(8)))  short bf16x8;
typedef __attribute__((ext_vector_type(4)))  unsigned u32x4;

#define LAMBDA_INIT 0.7836057665316244f
#define OUT_SCALE   0.21639423346837556f

__device__ __forceinline__ unsigned short f2bf(float f) {
  unsigned int u = __float_as_uint(f);
  u += 0x7FFFu + ((u >> 16) & 1u);
  return (unsigned short)(u >> 16);
}
__device__ __forceinline__ float bf2f(unsigned short h) {
  return __uint_as_float(((unsigned int)h) << 16);
}
__device__ __forceinline__ unsigned cvt_pk_bf16(float a, float b) {
  unsigned r;
  asm("v_cvt_pk_bf16_f32 %0, %1, %2" : "=v"(r) : "v"(a), "v"(b));
  return r;
}

// ---------------- Kernel 1: QKV projection (bf16 MFMA GEMM) ---------------
// R4-proven structure: M-tile 64, N=128, grid (128, 3) = 384 blocks.
// Register-prefetch of next K-slab hides global latency under MFMA.
// q gets SCALE=0.125 folded in (exact power of 2).
#define K1_LDP 40

__global__ __launch_bounds__(256) void qkv_proj(
    const float* __restrict__ x, const float* __restrict__ wq,
    const float* __restrict__ wk, const float* __restrict__ wv,
    unsigned short* __restrict__ qb, unsigned short* __restrict__ kb,
    unsigned short* __restrict__ vt)
{
  __shared__ __align__(16) unsigned short Ah[64 * K1_LDP];
  __shared__ __align__(16) unsigned short Bh[128 * K1_LDP];
  const int which = blockIdx.y;                 // 0=q,1=k,2=v
  const float* w = (which == 0) ? wq : ((which == 1) ? wk : wv);
  const int m0 = blockIdx.x * 64;
  const int tid = threadIdx.x;
  const int lane = tid & 63, wid = tid >> 6;
  const int wm = wid >> 1, wn = wid & 1;        // wave tile 32(m) x 64(n)
  const int fr = lane & 15, fq = lane >> 4;
  const int fk = fq << 3;

  f32x4 acc[2][4];
  #pragma unroll
  for (int i = 0; i < 2; ++i)
    #pragma unroll
    for (int j = 0; j < 4; ++j) acc[i][j] = (f32x4){0.f, 0.f, 0.f, 0.f};

  f32x4 arg[2], brg[4];
  #pragma unroll
  for (int c = 0; c < 2; ++c) {
    int id = tid + c * 256, r = id >> 3, c4 = (id & 7) << 2;
    arg[c] = *reinterpret_cast<const f32x4*>(&x[(size_t)(m0 + r) * D_MODEL + c4]);
  }
  #pragma unroll
  for (int c = 0; c < 4; ++c) {
    int id = tid + c * 256, n = id & 127, kc = (id >> 7) << 2;
    #pragma unroll
    for (int j = 0; j < 4; ++j) brg[c][j] = w[(size_t)(kc + j) * HD + n];
  }

  for (int it = 0; it < 64; ++it) {
    #pragma unroll
    for (int c = 0; c < 2; ++c) {
      int id = tid + c * 256, r = id >> 3, c4 = (id & 7) << 2;
      uint2 ph;
      ph.x = cvt_pk_bf16(arg[c][0], arg[c][1]);
      ph.y = cvt_pk_bf16(arg[c][2], arg[c][3]);
      *reinterpret_cast<uint2*>(&Ah[r * K1_LDP + c4]) = ph;
    }
    #pragma unroll
    for (int c = 0; c < 4; ++c) {
      int id = tid + c * 256, n = id & 127, kc = (id >> 7) << 2;
      uint2 ph;
      ph.x = cvt_pk_bf16(brg[c][0], brg[c][1]);
      ph.y = cvt_pk_bf16(brg[c][2], brg[c][3]);
      *reinterpret_cast<uint2*>(&Bh[n * K1_LDP + kc]) = ph;
    }
    __syncthreads();
    if (it < 63) {
      int k0n = (it + 1) * 32;
      #pragma unroll
      for (int c = 0; c < 2; ++c) {
        int id = tid + c * 256, r = id >> 3, c4 = (id & 7) << 2;
        arg[c] = *reinterpret_cast<const f32x4*>(&x[(size_t)(m0 + r) * D_MODEL + k0n + c4]);
      }
      #pragma unroll
      for (int c = 0; c < 4; ++c) {
        int id = tid + c * 256, n = id & 127, kc = (id >> 7) << 2;
        #pragma unroll
        for (int j = 0; j < 4; ++j) brg[c][j] = w[(size_t)(k0n + kc + j) * HD + n];
      }
    }
    bf16x8 ah[2], bh[4];
    #pragma unroll
    for (int mi = 0; mi < 2; ++mi)
      ah[mi] = *reinterpret_cast<bf16x8*>(&Ah[(wm * 32 + mi * 16 + fr) * K1_LDP + fk]);
    #pragma unroll
    for (int ni = 0; ni < 4; ++ni)
      bh[ni] = *reinterpret_cast<bf16x8*>(&Bh[(wn * 64 + ni * 16 + fr) * K1_LDP + fk]);
    #pragma unroll
    for (int mi = 0; mi < 2; ++mi)
      #pragma unroll
      for (int ni = 0; ni < 4; ++ni)
        acc[mi][ni] = __builtin_amdgcn_mfma_f32_16x16x32_bf16(ah[mi], bh[ni], acc[mi][ni], 0, 0, 0);
    __syncthreads();
  }
  #pragma unroll
  for (int mi = 0; mi < 2; ++mi)
    #pragma unroll
    for (int ni = 0; ni < 4; ++ni) {
      int n = wn * 64 + ni * 16 + fr;
      #pragma unroll
      for (int r = 0; r < 4; ++r) {
        int m = m0 + wm * 32 + mi * 16 + fq * 4 + r;
        float vv = acc[mi][ni][r];
        if (which == 2) {
          int bb = m >> 12, t = m & 4095;
          vt[((size_t)bb * HD + n) * T_SEQ + t] = f2bf(vv);
        } else if (which == 0) {
          qb[(size_t)m * HD + n] = f2bf(vv * 0.125f);   // fold softmax scale
        } else {
          kb[(size_t)m * HD + n] = f2bf(vv);
        }
      }
    }
}

// ---------------- Kernel 2: per-wave flash partials -----------------------
// wave decodes (b, qt_raw, g, sp); qt = 127 - qt_raw so heavy tiles launch
// first. K prefetch one tile ahead; V loaded early; no LDS, no syncthreads.
template<int LOG2S>
__global__ __launch_bounds__(256, 2) void diff_attn_part(
    const unsigned short* __restrict__ qb, const unsigned short* __restrict__ kb,
    const unsigned short* __restrict__ vt,
    unsigned short* __restrict__ po, float* __restrict__ pm, float* __restrict__ pl)
{
  constexpr int S = 1 << LOG2S;
  const int tid = threadIdx.x, lane = tid & 63, wid = tid >> 6;
  const int wave_id = blockIdx.x * 4 + wid;
  const int sp = wave_id & (S - 1);
  const int g  = (wave_id >> LOG2S) & 1;
  const int qt_raw = (wave_id >> (LOG2S + 1)) & 127;
  const int b  = wave_id >> (LOG2S + 8);
  const int qt = 127 - qt_raw;                  // heavy-first scheduling
  const int slot = (((b * 128 + qt) * 2 + g) << LOG2S) + sp;
  const int lq = lane & 31, lh = lane >> 5;
  const int q0 = qt * 32;
  const int n  = qt + 1;
  const int kt0 = (n * sp) >> LOG2S;
  const int kt1 = (n * (sp + 1)) >> LOG2S;

  // Q as B-operand: col=q=lq, k = ks*16 + lh*8 + e
  bf16x8 qf[4];
  const unsigned short* qp = qb + ((size_t)b * T_SEQ + q0 + lq) * HD + g * 64 + lh * 8;
  #pragma unroll
  for (int ks = 0; ks < 4; ++ks) qf[ks] = *reinterpret_cast<const bf16x8*>(qp + ks * 16);

  f32x16 acc[4];
  #pragma unroll
  for (int v = 0; v < 4; ++v)
    #pragma unroll
    for (int r = 0; r < 16; ++r) acc[v][r] = 0.f;
  float mrun = -1e30f, lrun = 0.f;

  const unsigned short* kp = kb + ((size_t)b * T_SEQ + lq) * HD + g * 64 + lh * 8;
  const unsigned short* vp = vt + ((size_t)b * HD + lq) * T_SEQ + lh * 8;

  bf16x8 kf[4];
  if (kt0 < kt1) {
    #pragma unroll
    for (int ks = 0; ks < 4; ++ks)
      kf[ks] = *reinterpret_cast<const bf16x8*>(kp + (size_t)kt0 * 32 * HD + ks * 16);
  }

  for (int kt = kt0; kt < kt1; ++kt) {
    const int kv0 = kt * 32;
    // V loads for this tile + K loads for next tile: issued before the
    // compute so their L2 latency hides under softmax VALU.
    bf16x8 vfa[4], vfb[4];
    #pragma unroll
    for (int vcb = 0; vcb < 4; ++vcb) {
      vfa[vcb] = *reinterpret_cast<const bf16x8*>(vp + (size_t)vcb * 32 * T_SEQ + kv0);
      vfb[vcb] = *reinterpret_cast<const bf16x8*>(vp + (size_t)vcb * 32 * T_SEQ + kv0 + 16);
    }
    bf16x8 kfn[4];
    const bool more = (kt + 1 < kt1);
    if (more) {
      #pragma unroll
      for (int ks = 0; ks < 4; ++ks)
        kfn[ks] = *reinterpret_cast<const bf16x8*>(kp + (size_t)(kv0 + 32) * HD + ks * 16);
    }
    // QK^T (kf arrived: loaded one iteration ago)
    f32x16 sc;
    #pragma unroll
    for (int r = 0; r < 16; ++r) sc[r] = 0.f;
    #pragma unroll
    for (int ks = 0; ks < 4; ++ks)
      sc = __builtin_amdgcn_mfma_f32_32x32x16_bf16(kf[ks], qf[ks], sc, 0, 0, 0);

    float p[16];
    if (kt == n - 1) {      // diagonal tile: mask kv_local > q_local
      #pragma unroll
      for (int r = 0; r < 16; ++r) {
        int rloc = (r & 3) + 8 * (r >> 2) + 4 * lh;
        p[r] = (rloc > lq) ? -1e30f : sc[r];
      }
    } else {
      #pragma unroll
      for (int r = 0; r < 16; ++r) p[r] = sc[r];
    }
    // column max over 32 rows (16 local + partner half)
    float t16[16];
    #pragma unroll
    for (int r = 0; r < 16; ++r) t16[r] = p[r];
    #pragma unroll
    for (int st = 8; st >= 1; st >>= 1)
      #pragma unroll
      for (int r = 0; r < 8; ++r)
        if (r < st) t16[r] = fmaxf(t16[r], t16[r + st]);
    float pmax = fmaxf(t16[0], __shfl_xor(t16[0], 32));
    if (__any(pmax > mrun + 8.f)) {          // T13 defer-max
      float mn = fmaxf(mrun, pmax);
      float al = __expf(mrun - mn);
      lrun *= al;
      #pragma unroll
      for (int v = 0; v < 4; ++v)
        #pragma unroll
        for (int r = 0; r < 16; ++r) acc[v][r] *= al;
      mrun = mn;
    }
    float psum;
    {
      float s16[16];
      #pragma unroll
      for (int r = 0; r < 16; ++r) { p[r] = __expf(p[r] - mrun); s16[r] = p[r]; }
      #pragma unroll
      for (int st = 8; st >= 1; st >>= 1)
        #pragma unroll
        for (int r = 0; r < 8; ++r)
          if (r < st) s16[r] += s16[r + st];
      psum = s16[0];
    }
    lrun += psum + __shfl_xor(psum, 32);     // full column sum

    // pack P -> B-frags via partner exchange (shfl_xor 32)
    unsigned A0 = cvt_pk_bf16(p[0],  p[1]),  A1 = cvt_pk_bf16(p[2],  p[3]);
    unsigned A2 = cvt_pk_bf16(p[4],  p[5]),  A3 = cvt_pk_bf16(p[6],  p[7]);
    unsigned A4 = cvt_pk_bf16(p[8],  p[9]),  A5 = cvt_pk_bf16(p[10], p[11]);
    unsigned A6 = cvt_pk_bf16(p[12], p[13]), A7 = cvt_pk_bf16(p[14], p[15]);
    unsigned pA0 = (unsigned)__shfl_xor((int)A0, 32);
    unsigned pA1 = (unsigned)__shfl_xor((int)A1, 32);
    unsigned pA2 = (unsigned)__shfl_xor((int)A2, 32);
    unsigned pA3 = (unsigned)__shfl_xor((int)A3, 32);
    unsigned pA4 = (unsigned)__shfl_xor((int)A4, 32);
    unsigned pA5 = (unsigned)__shfl_xor((int)A5, 32);
    unsigned pA6 = (unsigned)__shfl_xor((int)A6, 32);
    unsigned pA7 = (unsigned)__shfl_xor((int)A7, 32);
    u32x4 w0, w1;
    w0[0] = lh ? pA2 : A0;  w0[1] = lh ? pA3 : A1;
    w0[2] = lh ? A2  : pA0; w0[3] = lh ? A3  : pA1;
    w1[0] = lh ? pA6 : A4;  w1[1] = lh ? pA7 : A5;
    w1[2] = lh ? A6  : pA4; w1[3] = lh ? A7  : pA5;
    bf16x8 pb0 = *reinterpret_cast<bf16x8*>(&w0);
    bf16x8 pb1 = *reinterpret_cast<bf16x8*>(&w1);
    // PV (O^T = V^T * P), V already in regs
    #pragma unroll
    for (int vcb = 0; vcb < 4; ++vcb) {
      acc[vcb] = __builtin_amdgcn_mfma_f32_32x32x16_bf16(vfa[vcb], pb0, acc[vcb], 0, 0, 0);
      acc[vcb] = __builtin_amdgcn_mfma_f32_32x32x16_bf16(vfb[vcb], pb1, acc[vcb], 0, 0, 0);
    }
    if (more) {
      #pragma unroll
      for (int ks = 0; ks < 4; ++ks) kf[ks] = kfn[ks];
    }
  }
  // write partial: o^T[vc][q] bf16 + stats
  const size_t pbase = (size_t)slot * (HD * 32);
  #pragma unroll
  for (int vcb = 0; vcb < 4; ++vcb)
    #pragma unroll
    for (int r = 0; r < 16; ++r) {
      int vc = vcb * 32 + (r & 3) + 8 * (r >> 2) + 4 * lh;
      po[pbase + (size_t)vc * 32 + lq] = f2bf(acc[vcb][r]);
    }
  if (lane < 32) {
    pm[slot * 32 + lq] = mrun;
    pl[slot * 32 + lq] = lrun;
  }
}

// ---------------- Kernel 3: merge partials + diff + RMS + store -----------
template<int LOG2S>
__global__ __launch_bounds__(256) void diff_merge(
    const unsigned short* __restrict__ po, const float* __restrict__ pm,
    const float* __restrict__ pl,
    const float* __restrict__ lq1, const float* __restrict__ lq2,
    const float* __restrict__ lk1, const float* __restrict__ lk2,
    const float* __restrict__ lnw, float* __restrict__ out)
{
  constexpr int S = 1 << LOG2S;
  __shared__ float red[4][32];
  const int tid = threadIdx.x, lane = tid & 63, wid = tid >> 6;
  const int q = tid & 31, vg = tid >> 5;       // vc = vg*16 + i
  const int bq = blockIdx.x;                    // b*128 + qt
  const int b = bq >> 7, qt = bq & 127;

  float la = lq1[lane] * lk1[lane];
  float lb = lq2[lane] * lk2[lane];
  #pragma unroll
  for (int off = 32; off >= 1; off >>= 1) {
    la += __shfl_xor(la, off);
    lb += __shfl_xor(lb, off);
  }
  const float lam = __expf(la) - __expf(lb) + LAMBDA_INIT;

  const int p1 = (bq * 2 + 0) * S;
  const int p2 = (bq * 2 + 1) * S;
  float w1[S], w2[S];
  {
    float ms[S];
    #pragma unroll
    for (int s = 0; s < S; ++s) ms[s] = pm[(p1 + s) * 32 + q];
    float M = ms[0];
    #pragma unroll
    for (int s = 1; s < S; ++s) M = fmaxf(M, ms[s]);
    float L = 0.f;
    #pragma unroll
    for (int s = 0; s < S; ++s) { w1[s] = __expf(ms[s] - M); L += w1[s] * pl[(p1 + s) * 32 + q]; }
    float inv = 1.f / L;
    #pragma unroll
    for (int s = 0; s < S; ++s) w1[s] *= inv;
  }
  {
    float ms[S];
    #pragma unroll
    for (int s = 0; s < S; ++s) ms[s] = pm[(p2 + s) * 32 + q];
    float M = ms[0];
    #pragma unroll
    for (int s = 1; s < S; ++s) M = fmaxf(M, ms[s]);
    float L = 0.f;
    #pragma unroll
    for (int s = 0; s < S; ++s) { w2[s] = __expf(ms[s] - M); L += w2[s] * pl[(p2 + s) * 32 + q]; }
    float inv = lam / L;
    #pragma unroll
    for (int s = 0; s < S; ++s) w2[s] *= inv;
  }
  float d[16], ss = 0.f;
  #pragma unroll
  for (int i = 0; i < 16; ++i) {
    int vc = vg * 16 + i;
    float a1 = 0.f, a2 = 0.f;
    #pragma unroll
    for (int s = 0; s < S; ++s) {
      a1 += w1[s] * bf2f(po[(size_t)(p1 + s) * (HD * 32) + (size_t)vc * 32 + q]);
      a2 += w2[s] * bf2f(po[(size_t)(p2 + s) * (HD * 32) + (size_t)vc * 32 + q]);
    }
    d[i] = a1 - a2;
    ss += d[i] * d[i];
  }
  ss += __shfl_xor(ss, 32);
  if (lane < 32) red[wid][q] = ss;
  __syncthreads();
  float tot = red[0][q] + red[1][q] + red[2][q] + red[3][q];
  float rinv = 1.f / sqrtf(tot * (1.0f / HD) + 1e-5f);
  float* op = out + ((size_t)b * T_SEQ + qt * 32 + q) * HD + vg * 16;
  #pragma unroll
  for (int i = 0; i < 16; ++i) op[i] = OUT_SCALE * d[i] * rinv * lnw[vg * 16 + i];
}

extern "C" void kernel_launch(void* const* d_in, const int* in_sizes, int n_in,
                              void* d_out, int out_size, void* d_ws, size_t ws_size,
                              hipStream_t stream) {
  const float* x   = (const float*)d_in[0];
  const float* wq  = (const float*)d_in[1];
  const float* wk  = (const float*)d_in[2];
  const float* wv  = (const float*)d_in[3];
  const float* lq1 = (const float*)d_in[4];
  const float* lq2 = (const float*)d_in[5];
  const float* lk1 = (const float*)d_in[6];
  const float* lk2 = (const float*)d_in[7];
  const float* lnw = (const float*)d_in[8];
  float* out = (float*)d_out;

  const size_t N = (size_t)NB * T_SEQ * HD;     // 1,048,576
  int log2S = 3;
  for (; log2S > 0; --log2S) {
    size_t parts = ((size_t)NB * 128 * 2) << log2S;
    size_t need = 3 * N * 2 + parts * (HD * 32) * 2 + parts * 32 * 8;
    if (need <= ws_size) break;
  }
  const size_t parts = ((size_t)NB * 128 * 2) << log2S;

  unsigned short* qb = (unsigned short*)d_ws;
  unsigned short* kb = qb + N;
  unsigned short* vt = kb + N;
  unsigned short* po = vt + N;
  float* pm = (float*)(po + parts * (HD * 32));
  float* pl = pm + parts * 32;

  qkv_proj<<<dim3(128, 3), 256, 0, stream>>>(x, wq, wk, wv, qb, kb, vt);
  const int ablocks = (int)(parts / 4);
  switch (log2S) {
    case 3:
      diff_attn_part<3><<<dim3(ablocks), 256, 0, stream>>>(qb, kb, vt, po, pm, pl);
      diff_merge<3><<<dim3(NB * 128), 256, 0, stream>>>(po, pm, pl, lq1, lq2, lk1, lk2, lnw, out);
      break;
    case 2:
      diff_attn_part<2><<<dim3(ablocks), 256, 0, stream>>>(qb, kb, vt, po, pm, pl);
      diff_merge<2><<<dim3(NB * 128), 256, 0, stream>>>(po, pm, pl, lq1, lq2, lk1, lk2, lnw, out);
      break;
    case 1:
      diff_attn_part<1><<<dim3(ablocks), 256, 0, stream>>>(qb, kb, vt, po, pm, pl);
      diff_merge<1><<<dim3(NB * 128), 256, 0, stream>>>(po, pm, pl, lq1, lq2, lk1, lk2, lnw, out);
      break;
    default:
      diff_attn_part<0><<<dim3(ablocks), 256, 0, stream>>>(qb, kb, vt, po, pm, pl);
      diff_merge<0><<<dim3(NB * 128), 256, 0, stream>>>(po, pm, pl, lq1, lq2, lk1, lk2, lnw, out);
      break;
  }
}

// Round 7
// 87.649 us; speedup vs baseline: 2.0975x; 1.3936x over previous
//
#include <hip/hip_runtime.h>
#include <stdint.h>

#define T_SEQ 4096
#define NB 2
#define D_MODEL 2048
#define HD 128

typedef __attribute__((ext_vector_type(4)))  float f32x4;
typedef __attribute__((ext_vector_type(16))) float f32x16;
typedef __attribute__((ext_vector_type(8)))  short bf16x8;
typedef __attribute__((ext_vector_type(4)))  unsigned u32x4;

#define LAMBDA_INIT 0.7836057665316244f
#define OUT_SCALE   0.21639423346837556f

__device__ __forceinline__ unsigned short f2bf(float f) {
  unsigned int u = __float_as_uint(f);
  u += 0x7FFFu + ((u >> 16) & 1u);
  return (unsigned short)(u >> 16);
}
__device__ __forceinline__ float bf2f(unsigned short h) {
  return __uint_as_float(((unsigned int)h) << 16);
}
__device__ __forceinline__ unsigned cvt_pk_bf16(float a, float b) {
  unsigned r;
  asm("v_cvt_pk_bf16_f32 %0, %1, %2" : "=v"(r) : "v"(a), "v"(b));
  return r;
}

// ---------------- Kernel 1: QKV projection (bf16 MFMA GEMM) ---------------
// M=64, N=128, grid (128,3). Conflict-free LDS layouts:
//   A: [row][kg] 16B chunks  (kg = k/8)
//   B: [kg][n]  16B chunks, n-dim padded to 132 (kg-groups offset banks)
// K and V epilogues scatter into MFMA-fragment order (1KB/fragment) so the
// attention kernel's K/V loads are fully coalesced.
__global__ __launch_bounds__(256) void qkv_proj(
    const float* __restrict__ x, const float* __restrict__ wq,
    const float* __restrict__ wk, const float* __restrict__ wv,
    unsigned short* __restrict__ qb, unsigned short* __restrict__ kS,
    unsigned short* __restrict__ vS)
{
  __shared__ __align__(16) unsigned short Ah[64 * 4 * 8];       // [row][kg][8]
  __shared__ __align__(16) unsigned short Bh[4 * 132 * 8];      // [kg][n(pad132)][8]
  const int which = blockIdx.y;                 // 0=q,1=k,2=v
  const float* w = (which == 0) ? wq : ((which == 1) ? wk : wv);
  const int m0 = blockIdx.x * 64;
  const int tid = threadIdx.x;
  const int lane = tid & 63, wid = tid >> 6;
  const int wm = wid >> 1, wn = wid & 1;        // wave tile 32(m) x 64(n)
  const int fr = lane & 15, fq = lane >> 4;

  f32x4 acc[2][4];
  #pragma unroll
  for (int i = 0; i < 2; ++i)
    #pragma unroll
    for (int j = 0; j < 4; ++j) acc[i][j] = (f32x4){0.f, 0.f, 0.f, 0.f};

  f32x4 arg[2], brg[4];
  #pragma unroll
  for (int c = 0; c < 2; ++c) {
    int id = tid + c * 256, r = id >> 3, c4 = (id & 7) << 2;
    arg[c] = *reinterpret_cast<const f32x4*>(&x[(size_t)(m0 + r) * D_MODEL + c4]);
  }
  #pragma unroll
  for (int c = 0; c < 4; ++c) {
    int id = tid + c * 256, n = id & 127, kc = (id >> 7) << 2;
    #pragma unroll
    for (int j = 0; j < 4; ++j) brg[c][j] = w[(size_t)(kc + j) * HD + n];
  }

  for (int it = 0; it < 64; ++it) {
    #pragma unroll
    for (int c = 0; c < 2; ++c) {
      int id = tid + c * 256, r = id >> 3, ac = (id & 7) << 2;
      uint2 ph;
      ph.x = cvt_pk_bf16(arg[c][0], arg[c][1]);
      ph.y = cvt_pk_bf16(arg[c][2], arg[c][3]);
      *reinterpret_cast<uint2*>(&Ah[(r * 4 + (ac >> 3)) * 8 + (ac & 4)]) = ph;
    }
    #pragma unroll
    for (int c = 0; c < 4; ++c) {
      int id = tid + c * 256, n = id & 127, kc = (id >> 7) << 2;
      uint2 ph;
      ph.x = cvt_pk_bf16(brg[c][0], brg[c][1]);
      ph.y = cvt_pk_bf16(brg[c][2], brg[c][3]);
      *reinterpret_cast<uint2*>(&Bh[((kc >> 3) * 132 + n) * 8 + (kc & 4)]) = ph;
    }
    __syncthreads();
    if (it < 63) {
      int k0n = (it + 1) * 32;
      #pragma unroll
      for (int c = 0; c < 2; ++c) {
        int id = tid + c * 256, r = id >> 3, c4 = (id & 7) << 2;
        arg[c] = *reinterpret_cast<const f32x4*>(&x[(size_t)(m0 + r) * D_MODEL + k0n + c4]);
      }
      #pragma unroll
      for (int c = 0; c < 4; ++c) {
        int id = tid + c * 256, n = id & 127, kc = (id >> 7) << 2;
        #pragma unroll
        for (int j = 0; j < 4; ++j) brg[c][j] = w[(size_t)(k0n + kc + j) * HD + n];
      }
    }
    bf16x8 ah[2], bh[4];
    #pragma unroll
    for (int mi = 0; mi < 2; ++mi)
      ah[mi] = *reinterpret_cast<bf16x8*>(&Ah[((wm * 32 + mi * 16 + fr) * 4 + fq) * 8]);
    #pragma unroll
    for (int ni = 0; ni < 4; ++ni)
      bh[ni] = *reinterpret_cast<bf16x8*>(&Bh[(fq * 132 + wn * 64 + ni * 16 + fr) * 8]);
    #pragma unroll
    for (int mi = 0; mi < 2; ++mi)
      #pragma unroll
      for (int ni = 0; ni < 4; ++ni)
        acc[mi][ni] = __builtin_amdgcn_mfma_f32_16x16x32_bf16(ah[mi], bh[ni], acc[mi][ni], 0, 0, 0);
    __syncthreads();
  }
  #pragma unroll
  for (int mi = 0; mi < 2; ++mi)
    #pragma unroll
    for (int ni = 0; ni < 4; ++ni) {
      int n = wn * 64 + ni * 16 + fr;
      #pragma unroll
      for (int r = 0; r < 4; ++r) {
        int m = m0 + wm * 32 + mi * 16 + fq * 4 + r;
        float vv = acc[mi][ni][r];
        int bb = m >> 12, tt = m & 4095;
        int kt = tt >> 5, kvl = tt & 31;
        if (which == 0) {
          qb[(size_t)m * HD + n] = f2bf(vv * 0.125f);   // fold softmax scale
        } else if (which == 1) {
          // K fragment scatter: frag ((b*128+kt)*2+g)*4+ks, lane kvl+32*r8
          int g = n >> 6, hl = n & 63;
          int ks = hl >> 4, r8 = (hl >> 3) & 1, e = hl & 7;
          size_t idx = ((((((size_t)bb * 128 + kt) * 2 + g) * 4) + ks) << 9)
                     + (size_t)(kvl + 32 * r8) * 8 + e;
          kS[idx] = f2bf(vv);
        } else {
          // V fragment scatter: frag (b*128+kt)*8 + vcb*2 + f, lane (n&31)+32*r8
          int f = kvl >> 4, r8 = (kvl >> 3) & 1, e = kvl & 7;
          int vcb = n >> 5;
          size_t idx = (((((size_t)bb * 128 + kt) * 8) + vcb * 2 + f) << 9)
                     + (size_t)((n & 31) + 32 * r8) * 8 + e;
          vS[idx] = f2bf(vv);
        }
      }
    }
}

// ---------------- Kernel 2: per-wave flash partials -----------------------
// K/V read from fragment-swizzled buffers: every load is a coalesced
// 64-lane x 16B (1KB) read. S=8 kv-splits, heavy-first, K prefetch 1 tile.
template<int LOG2S>
__global__ __launch_bounds__(256, 2) void diff_attn_part(
    const unsigned short* __restrict__ qb, const unsigned short* __restrict__ kS,
    const unsigned short* __restrict__ vS,
    unsigned short* __restrict__ po, float* __restrict__ pm, float* __restrict__ pl)
{
  constexpr int S = 1 << LOG2S;
  const int tid = threadIdx.x, lane = tid & 63, wid = tid >> 6;
  const int wave_id = blockIdx.x * 4 + wid;
  const int sp = wave_id & (S - 1);
  const int g  = (wave_id >> LOG2S) & 1;
  const int qt_raw = (wave_id >> (LOG2S + 1)) & 127;
  const int b  = wave_id >> (LOG2S + 8);
  const int qt = 127 - qt_raw;                  // heavy-first scheduling
  const int slot = (((b * 128 + qt) * 2 + g) << LOG2S) + sp;
  const int lq = lane & 31, lh = lane >> 5;
  const int q0 = qt * 32;
  const int n  = qt + 1;
  const int kt0 = (n * sp) >> LOG2S;
  const int kt1 = (n * (sp + 1)) >> LOG2S;

  // Q as B-operand: col=q=lq, k = ks*16 + lh*8 + e (row-major gather, once)
  bf16x8 qf[4];
  const unsigned short* qp = qb + ((size_t)b * T_SEQ + q0 + lq) * HD + g * 64 + lh * 8;
  #pragma unroll
  for (int ks = 0; ks < 4; ++ks) qf[ks] = *reinterpret_cast<const bf16x8*>(qp + ks * 16);

  f32x16 acc[4];
  #pragma unroll
  for (int v = 0; v < 4; ++v)
    #pragma unroll
    for (int r = 0; r < 16; ++r) acc[v][r] = 0.f;
  float mrun = -1e30f, lrun = 0.f;

  // fragment bases (ushort units; 512 ushorts = 1KB per fragment)
  const unsigned short* kbase = kS + ((size_t)(b * 128) * 2 + g) * 4 * 512 + lane * 8;
  const unsigned short* vbase = vS + (size_t)(b * 128) * 8 * 512 + lane * 8;
  // per-kt strides: K: 2*4*512 (both g), V: 8*512
  #define KFRAG(kt, ks) (kbase + ((size_t)(kt) * 8 + (ks)) * 512)
  #define VFRAG(kt, f)  (vbase + ((size_t)(kt) * 8 + (f)) * 512)

  bf16x8 kf[4];
  if (kt0 < kt1) {
    #pragma unroll
    for (int ks = 0; ks < 4; ++ks)
      kf[ks] = *reinterpret_cast<const bf16x8*>(KFRAG(kt0, ks));
  }

  for (int kt = kt0; kt < kt1; ++kt) {
    // V fragments for this tile (coalesced), K for next tile
    bf16x8 vfa[4], vfb[4];
    #pragma unroll
    for (int vcb = 0; vcb < 4; ++vcb) {
      vfa[vcb] = *reinterpret_cast<const bf16x8*>(VFRAG(kt, vcb * 2));
      vfb[vcb] = *reinterpret_cast<const bf16x8*>(VFRAG(kt, vcb * 2 + 1));
    }
    bf16x8 kfn[4];
    const bool more = (kt + 1 < kt1);
    if (more) {
      #pragma unroll
      for (int ks = 0; ks < 4; ++ks)
        kfn[ks] = *reinterpret_cast<const bf16x8*>(KFRAG(kt + 1, ks));
    }
    f32x16 sc;
    #pragma unroll
    for (int r = 0; r < 16; ++r) sc[r] = 0.f;
    #pragma unroll
    for (int ks = 0; ks < 4; ++ks)
      sc = __builtin_amdgcn_mfma_f32_32x32x16_bf16(kf[ks], qf[ks], sc, 0, 0, 0);

    float p[16];
    if (kt == n - 1) {      // diagonal tile: mask kv_local > q_local
      #pragma unroll
      for (int r = 0; r < 16; ++r) {
        int rloc = (r & 3) + 8 * (r >> 2) + 4 * lh;
        p[r] = (rloc > lq) ? -1e30f : sc[r];
      }
    } else {
      #pragma unroll
      for (int r = 0; r < 16; ++r) p[r] = sc[r];
    }
    // column max over 32 rows (16 local + partner half)
    float t16[16];
    #pragma unroll
    for (int r = 0; r < 16; ++r) t16[r] = p[r];
    #pragma unroll
    for (int st = 8; st >= 1; st >>= 1)
      #pragma unroll
      for (int r = 0; r < 8; ++r)
        if (r < st) t16[r] = fmaxf(t16[r], t16[r + st]);
    float pmax = fmaxf(t16[0], __shfl_xor(t16[0], 32));
    if (__any(pmax > mrun + 8.f)) {          // T13 defer-max
      float mn = fmaxf(mrun, pmax);
      float al = __expf(mrun - mn);
      lrun *= al;
      #pragma unroll
      for (int v = 0; v < 4; ++v)
        #pragma unroll
        for (int r = 0; r < 16; ++r) acc[v][r] *= al;
      mrun = mn;
    }
    float psum;
    {
      float s16[16];
      #pragma unroll
      for (int r = 0; r < 16; ++r) { p[r] = __expf(p[r] - mrun); s16[r] = p[r]; }
      #pragma unroll
      for (int st = 8; st >= 1; st >>= 1)
        #pragma unroll
        for (int r = 0; r < 8; ++r)
          if (r < st) s16[r] += s16[r + st];
      psum = s16[0];
    }
    lrun += psum + __shfl_xor(psum, 32);     // full column sum

    // pack P -> B-frags via partner exchange (shfl_xor 32)
    unsigned A0 = cvt_pk_bf16(p[0],  p[1]),  A1 = cvt_pk_bf16(p[2],  p[3]);
    unsigned A2 = cvt_pk_bf16(p[4],  p[5]),  A3 = cvt_pk_bf16(p[6],  p[7]);
    unsigned A4 = cvt_pk_bf16(p[8],  p[9]),  A5 = cvt_pk_bf16(p[10], p[11]);
    unsigned A6 = cvt_pk_bf16(p[12], p[13]), A7 = cvt_pk_bf16(p[14], p[15]);
    unsigned pA0 = (unsigned)__shfl_xor((int)A0, 32);
    unsigned pA1 = (unsigned)__shfl_xor((int)A1, 32);
    unsigned pA2 = (unsigned)__shfl_xor((int)A2, 32);
    unsigned pA3 = (unsigned)__shfl_xor((int)A3, 32);
    unsigned pA4 = (unsigned)__shfl_xor((int)A4, 32);
    unsigned pA5 = (unsigned)__shfl_xor((int)A5, 32);
    unsigned pA6 = (unsigned)__shfl_xor((int)A6, 32);
    unsigned pA7 = (unsigned)__shfl_xor((int)A7, 32);
    u32x4 w0, w1;
    w0[0] = lh ? pA2 : A0;  w0[1] = lh ? pA3 : A1;
    w0[2] = lh ? A2  : pA0; w0[3] = lh ? A3  : pA1;
    w1[0] = lh ? pA6 : A4;  w1[1] = lh ? pA7 : A5;
    w1[2] = lh ? A6  : pA4; w1[3] = lh ? A7  : pA5;
    bf16x8 pb0 = *reinterpret_cast<bf16x8*>(&w0);
    bf16x8 pb1 = *reinterpret_cast<bf16x8*>(&w1);
    // PV (O^T = V^T * P)
    #pragma unroll
    for (int vcb = 0; vcb < 4; ++vcb) {
      acc[vcb] = __builtin_amdgcn_mfma_f32_32x32x16_bf16(vfa[vcb], pb0, acc[vcb], 0, 0, 0);
      acc[vcb] = __builtin_amdgcn_mfma_f32_32x32x16_bf16(vfb[vcb], pb1, acc[vcb], 0, 0, 0);
    }
    if (more) {
      #pragma unroll
      for (int ks = 0; ks < 4; ++ks) kf[ks] = kfn[ks];
    }
  }
  #undef KFRAG
  #undef VFRAG
  // write partial: o^T[vc][q] bf16 + stats
  const size_t pbase = (size_t)slot * (HD * 32);
  #pragma unroll
  for (int vcb = 0; vcb < 4; ++vcb)
    #pragma unroll
    for (int r = 0; r < 16; ++r) {
      int vc = vcb * 32 + (r & 3) + 8 * (r >> 2) + 4 * lh;
      po[pbase + (size_t)vc * 32 + lq] = f2bf(acc[vcb][r]);
    }
  if (lane < 32) {
    pm[slot * 32 + lq] = mrun;
    pl[slot * 32 + lq] = lrun;
  }
}

// ---------------- Kernel 3: merge partials + diff + RMS + store -----------
template<int LOG2S>
__global__ __launch_bounds__(256) void diff_merge(
    const unsigned short* __restrict__ po, const float* __restrict__ pm,
    const float* __restrict__ pl,
    const float* __restrict__ lq1, const float* __restrict__ lq2,
    const float* __restrict__ lk1, const float* __restrict__ lk2,
    const float* __restrict__ lnw, float* __restrict__ out)
{
  constexpr int S = 1 << LOG2S;
  __shared__ float red[4][32];
  const int tid = threadIdx.x, lane = tid & 63, wid = tid >> 6;
  const int q = tid & 31, vg = tid >> 5;       // vc = vg*16 + i
  const int bq = blockIdx.x;                    // b*128 + qt
  const int b = bq >> 7, qt = bq & 127;

  float la = lq1[lane] * lk1[lane];
  float lb = lq2[lane] * lk2[lane];
  #pragma unroll
  for (int off = 32; off >= 1; off >>= 1) {
    la += __shfl_xor(la, off);
    lb += __shfl_xor(lb, off);
  }
  const float lam = __expf(la) - __expf(lb) + LAMBDA_INIT;

  const int p1 = (bq * 2 + 0) * S;
  const int p2 = (bq * 2 + 1) * S;
  float w1[S], w2[S];
  {
    float ms[S];
    #pragma unroll
    for (int s = 0; s < S; ++s) ms[s] = pm[(p1 + s) * 32 + q];
    float M = ms[0];
    #pragma unroll
    for (int s = 1; s < S; ++s) M = fmaxf(M, ms[s]);
    float L = 0.f;
    #pragma unroll
    for (int s = 0; s < S; ++s) { w1[s] = __expf(ms[s] - M); L += w1[s] * pl[(p1 + s) * 32 + q]; }
    float inv = 1.f / L;
    #pragma unroll
    for (int s = 0; s < S; ++s) w1[s] *= inv;
  }
  {
    float ms[S];
    #pragma unroll
    for (int s = 0; s < S; ++s) ms[s] = pm[(p2 + s) * 32 + q];
    float M = ms[0];
    #pragma unroll
    for (int s = 1; s < S; ++s) M = fmaxf(M, ms[s]);
    float L = 0.f;
    #pragma unroll
    for (int s = 0; s < S; ++s) { w2[s] = __expf(ms[s] - M); L += w2[s] * pl[(p2 + s) * 32 + q]; }
    float inv = lam / L;
    #pragma unroll
    for (int s = 0; s < S; ++s) w2[s] *= inv;
  }
  float d[16], ss = 0.f;
  #pragma unroll
  for (int i = 0; i < 16; ++i) {
    int vc = vg * 16 + i;
    float a1 = 0.f, a2 = 0.f;
    #pragma unroll
    for (int s = 0; s < S; ++s) {
      a1 += w1[s] * bf2f(po[(size_t)(p1 + s) * (HD * 32) + (size_t)vc * 32 + q]);
      a2 += w2[s] * bf2f(po[(size_t)(p2 + s) * (HD * 32) + (size_t)vc * 32 + q]);
    }
    d[i] = a1 - a2;
    ss += d[i] * d[i];
  }
  ss += __shfl_xor(ss, 32);
  if (lane < 32) red[wid][q] = ss;
  __syncthreads();
  float tot = red[0][q] + red[1][q] + red[2][q] + red[3][q];
  float rinv = 1.f / sqrtf(tot * (1.0f / HD) + 1e-5f);
  float* op = out + ((size_t)b * T_SEQ + qt * 32 + q) * HD + vg * 16;
  #pragma unroll
  for (int i = 0; i < 16; ++i) op[i] = OUT_SCALE * d[i] * rinv * lnw[vg * 16 + i];
}

extern "C" void kernel_launch(void* const* d_in, const int* in_sizes, int n_in,
                              void* d_out, int out_size, void* d_ws, size_t ws_size,
                              hipStream_t stream) {
  const float* x   = (const float*)d_in[0];
  const float* wq  = (const float*)d_in[1];
  const float* wk  = (const float*)d_in[2];
  const float* wv  = (const float*)d_in[3];
  const float* lq1 = (const float*)d_in[4];
  const float* lq2 = (const float*)d_in[5];
  const float* lk1 = (const float*)d_in[6];
  const float* lk2 = (const float*)d_in[7];
  const float* lnw = (const float*)d_in[8];
  float* out = (float*)d_out;

  const size_t N = (size_t)NB * T_SEQ * HD;     // 1,048,576
  int log2S = 3;
  for (; log2S > 0; --log2S) {
    size_t parts = ((size_t)NB * 128 * 2) << log2S;
    size_t need = 3 * N * 2 + parts * (HD * 32) * 2 + parts * 32 * 8;
    if (need <= ws_size) break;
  }
  const size_t parts = ((size_t)NB * 128 * 2) << log2S;

  unsigned short* qb = (unsigned short*)d_ws;
  unsigned short* kS = qb + N;
  unsigned short* vS = kS + N;
  unsigned short* po = vS + N;
  float* pm = (float*)(po + parts * (HD * 32));
  float* pl = pm + parts * 32;

  qkv_proj<<<dim3(128, 3), 256, 0, stream>>>(x, wq, wk, wv, qb, kS, vS);
  const int ablocks = (int)(parts / 4);
  switch (log2S) {
    case 3:
      diff_attn_part<3><<<dim3(ablocks), 256, 0, stream>>>(qb, kS, vS, po, pm, pl);
      diff_merge<3><<<dim3(NB * 128), 256, 0, stream>>>(po, pm, pl, lq1, lq2, lk1, lk2, lnw, out);
      break;
    case 2:
      diff_attn_part<2><<<dim3(ablocks), 256, 0, stream>>>(qb, kS, vS, po, pm, pl);
      diff_merge<2><<<dim3(NB * 128), 256, 0, stream>>>(po, pm, pl, lq1, lq2, lk1, lk2, lnw, out);
      break;
    case 1:
      diff_attn_part<1><<<dim3(ablocks), 256, 0, stream>>>(qb, kS, vS, po, pm, pl);
      diff_merge<1><<<dim3(NB * 128), 256, 0, stream>>>(po, pm, pl, lq1, lq2, lk1, lk2, lnw, out);
      break;
    default:
      diff_attn_part<0><<<dim3(ablocks), 256, 0, stream>>>(qb, kS, vS, po, pm, pl);
      diff_merge<0><<<dim3(NB * 128), 256, 0, stream>>>(po, pm, pl, lq1, lq2, lk1, lk2, lnw, out);
      break;
  }
}